// Round 11
// baseline (681.197 us; speedup 1.0000x reference)
//
#include <hip/hip_runtime.h>

// ---- problem dims ----
#define IN_DIM 8193
#define OUT_DIM 4097
#define NB 1024
#define M1 8192    // GEMM1 M (rows 0..8191; row 8192 = hom handled separately)
#define KP1 8256   // 129 * 64 (B-side padded K)
#define M2 4096    // GEMM2 M (row 4096 handled separately)
#define KP2 4160   // 65 * 64

typedef __attribute__((ext_vector_type(8))) short short8;
typedef __attribute__((ext_vector_type(4))) float f32x4;

__device__ __forceinline__ unsigned short f2bf(float f) {
  unsigned int u = __float_as_uint(f);
  u = (u + 0x7fffu + ((u >> 16) & 1u)) >> 16;  // RNE
  return (unsigned short)u;
}
__device__ __forceinline__ float bf2f(unsigned short u) {
  return __uint_as_float(((unsigned int)u) << 16);
}

// ---- transpose+convert x -> xT bf16, FUSED hom row: zh[n] += Ainv[8192,:]·x[:,n] ----
__global__ __launch_bounds__(256) void transpose_cvt_zh_kernel(
    const float* __restrict__ src, unsigned short* __restrict__ dst,
    const float* __restrict__ arow, float* __restrict__ zh,
    int K, int N, int Kp) {
  __shared__ float tl[32][33];
  const int ntk = Kp >> 5;
  int bx = blockIdx.x % ntk;
  int by = blockIdx.x / ntk;
  int k0 = bx * 32, n0 = by * 32;
  int tx = threadIdx.x & 31, ty = threadIdx.x >> 5;
#pragma unroll
  for (int i = 0; i < 4; ++i) {
    int k = k0 + ty + i * 8;
    tl[ty + i * 8][tx] = (k < K) ? src[(size_t)k * N + n0 + tx] : 0.f;
  }
  const float av = (k0 + tx < K) ? arow[k0 + tx] : 0.f;
  __syncthreads();
#pragma unroll
  for (int i = 0; i < 4; ++i) {
    int n = n0 + ty + i * 8;
    float v = tl[tx][ty + i * 8];
    dst[(size_t)n * Kp + k0 + tx] = f2bf(v);
    float c = av * v;
#pragma unroll
    for (int m = 1; m <= 16; m <<= 1) c += __shfl_xor(c, m);
    if (tx == 0) atomicAdd(&zh[n], c);
  }
}

// ---- float4 zero ----
__global__ __launch_bounds__(256) void zero_kernel(float4* __restrict__ p, int n) {
  int i = blockIdx.x * 256 + threadIdx.x;
  if (i < n) p[i] = make_float4(0.f, 0.f, 0.f, 0.f);
}

// 8 exact-count scalar loads. "=&v" EARLY-CLOBBER is load-bearing: without it
// LLVM may alias an output reg with the input pointer pair (it assumes inputs
// die before outputs are written), so load #1 corrupts the address for loads
// #2..8 (R10 crash). Early-clobber also keeps the result regs allocated (live
// until next-phase ACVT use), so in-flight loads can't land in reused regs.
#define ALOAD8(R0, R1, R2, R3, R4, R5, R6, R7, P)                             \
  asm volatile("global_load_dword %0, %8, off\n\t"                            \
               "global_load_dword %1, %8, off offset:4\n\t"                   \
               "global_load_dword %2, %8, off offset:8\n\t"                   \
               "global_load_dword %3, %8, off offset:12\n\t"                  \
               "global_load_dword %4, %8, off offset:16\n\t"                  \
               "global_load_dword %5, %8, off offset:20\n\t"                  \
               "global_load_dword %6, %8, off offset:24\n\t"                  \
               "global_load_dword %7, %8, off offset:28\n\t"                  \
               : "=&v"(R0), "=&v"(R1), "=&v"(R2), "=&v"(R3), "=&v"(R4),       \
                 "=&v"(R5), "=&v"(R6), "=&v"(R7)                              \
               : "v"(P))

// ---- Fused-A 4-phase pipelined GEMM, exact 256-block grid ----
// Cpart(sp) (MROWS x NB) = f32A(256-tile bm, RNE->bf16 in staging)
//                          * Bt(256-tile bn, bf16 padded)^T over kt range.
// Tile 256x256, BK=64, 8 waves (2M x 4N), per-wave 128x64.
// LDS = 8 half-slots x 16KB: A written via reg->cvt->swizzled ds_write;
// B via global_load_lds (R7/R8-validated path).
// Pipeline (vmcnt ledger; issue order per iter is B:4 then A:32):
//   P1(t): wait vmcnt(32) = drain B(t)'s 4 (oldest), keep A(t+1)'s 32 flying
//   P4(t): wait vmcnt(4)  = drain A(t+1)'s 32, keep B(t+1)'s 4 flying;
//          ACVT(t+1) cvt+swizzled ds_write; issue A-loads(t+2)
// No A zero-guards: B's padded cols are zero (garbage*0=0); all A reads
// provably in-bounds for both GEMMs.
template <int NKT, int NSPLIT, int BMBITS, int MROWS>
__global__ __launch_bounds__(512) void gemm_fa(
    const float* __restrict__ Af,
    const unsigned short* __restrict__ Bt,
    float* __restrict__ C, int Kact, int Kp) {
  extern __shared__ unsigned short lds[];  // 8 * 8192 shorts = 128 KB
  const int tid = threadIdx.x;
  const int wid = tid >> 6;
  const int lane = tid & 63;
  const int b = blockIdx.x;
  const int x = b & 7, q = b >> 3;
  const int bm = (q & ((1 << BMBITS) - 1)) * 8 + x;
  const int bn = (q >> BMBITS) & 3;
  const int sp = q >> (BMBITS + 2);
  const int wm = (wid >> 2) << 7;  // 0 / 128
  const int wn = (wid & 3) << 6;   // 0 / 64 / 128 / 192

  const int qk = NKT / NSPLIT, rrk = NKT % NSPLIT;
  const int kt0 = sp * qk + (sp < rrk ? sp : rrk);
  const int T = qk + (sp < rrk ? 1 : 0);
  float* Cp = C + (size_t)sp * MROWS * NB;

  // fragment-read geometry (R7/R8-validated)
  const int g0 = ((lane >> 4) ^ (lane & 7)) * 8;        // kk=0
  const int g1 = ((4 + (lane >> 4)) ^ (lane & 7)) * 8;  // kk=1
  const int alo = (lane & 15) * 64;
  const int bhalf = (wn >> 7) << 1;
  const int ahalf = (wid >> 2) << 1;
  const int bsub = ((wn & 64) << 6) + alo;

  // A-staging geometry: thread -> (row 0..255, col-half 0/32)
  const int arow = tid >> 1;
  const int acol = (tid & 1) << 5;

#define STAGEB(TT)                                                             \
  do {                                                                         \
    const int tt_ = (TT);                                                      \
    const int kc_ = kt0 + (tt_ < T - 1 ? tt_ : T - 1);                         \
    const int par_ = tt_ & 1;                                                  \
    _Pragma("unroll")                                                          \
    for (int h_ = 0; h_ < 2; ++h_) {                                           \
      _Pragma("unroll")                                                        \
      for (int L_ = 0; L_ < 2; ++L_) {                                         \
        const int s_ = L_ * 512 + tid;                                         \
        const int row_ = s_ >> 3;                                              \
        const int gl_ = (s_ & 7) ^ (row_ & 7);                                 \
        const unsigned short* g_ =                                             \
            Bt + (size_t)((bn << 8) + (h_ << 7) + row_) * Kp + (kc_ << 6) +    \
            gl_ * 8;                                                           \
        unsigned short* l_ = lds + (4 + (h_ << 1) + par_) * 8192 +             \
                             (size_t)(L_ * 512 + wid * 64) * 8;                \
        __builtin_amdgcn_global_load_lds(                                      \
            (const __attribute__((address_space(1))) void*)g_,                 \
            (__attribute__((address_space(3))) void*)l_, 16, 0, 0);            \
      }                                                                        \
    }                                                                          \
  } while (0)

#define ALOAD(TT)                                                              \
  do {                                                                         \
    const int tt_ = (TT);                                                      \
    const int kc_ = kt0 + (tt_ < T - 1 ? tt_ : T - 1);                         \
    const float* p_ =                                                          \
        Af + (size_t)((bm << 8) + arow) * Kact + (kc_ << 6) + acol;            \
    ALOAD8(ar[0], ar[1], ar[2], ar[3], ar[4], ar[5], ar[6], ar[7], p_);        \
    ALOAD8(ar[8], ar[9], ar[10], ar[11], ar[12], ar[13], ar[14], ar[15],       \
           p_ + 8);                                                            \
    ALOAD8(ar[16], ar[17], ar[18], ar[19], ar[20], ar[21], ar[22], ar[23],     \
           p_ + 16);                                                           \
    ALOAD8(ar[24], ar[25], ar[26], ar[27], ar[28], ar[29], ar[30], ar[31],     \
           p_ + 24);                                                           \
  } while (0)

#define ACVT(TT)                                                               \
  do {                                                                         \
    const int parw_ = (TT) & 1;                                                \
    unsigned short* wb_ =                                                      \
        lds + (((arow >> 7) << 1) + parw_) * 8192 + (arow & 127) * 64;         \
    _Pragma("unroll")                                                          \
    for (int j_ = 0; j_ < 4; ++j_) {                                           \
      short8 pv_;                                                              \
      _Pragma("unroll")                                                        \
      for (int c_ = 0; c_ < 8; ++c_) pv_[c_] = (short)f2bf(ar[j_ * 8 + c_]);   \
      const int ph_ = ((acol >> 3) + j_) ^ (arow & 7);                         \
      *reinterpret_cast<short8*>(wb_ + ph_ * 8) = pv_;                         \
    }                                                                          \
  } while (0)

#define MFMA16(BV0, BV1, NF0, NF1)                                             \
  do {                                                                         \
    __builtin_amdgcn_s_setprio(1);                                             \
    _Pragma("unroll")                                                          \
    for (int mf_ = 0; mf_ < 8; ++mf_) {                                        \
      asm volatile("v_mfma_f32_16x16x32_bf16 %0, %1, %2, %0"                   \
                   : "+v"(acc[mf_][NF0]) : "v"(af[mf_]), "v"(BV0));            \
      asm volatile("v_mfma_f32_16x16x32_bf16 %0, %1, %2, %0"                   \
                   : "+v"(acc[mf_][NF1]) : "v"(af[mf_]), "v"(BV1));            \
    }                                                                          \
    __builtin_amdgcn_s_setprio(0);                                             \
  } while (0)

  f32x4 acc[8][4];
#pragma unroll
  for (int i = 0; i < 8; ++i)
#pragma unroll
    for (int j = 0; j < 4; ++j) acc[i][j] = (f32x4)(0.0f);

  float ar[32];
  // prologue: A(0) load+cvt+write; B(0) issue; A(1) loads in flight
  ALOAD(0);
  __builtin_amdgcn_sched_barrier(0);
  asm volatile("s_waitcnt vmcnt(0)" ::: "memory");
  __builtin_amdgcn_sched_barrier(0);
  ACVT(0);
  __builtin_amdgcn_sched_barrier(0);
  STAGEB(0);
  __builtin_amdgcn_sched_barrier(0);
  ALOAD(1);
  __builtin_amdgcn_sched_barrier(0);

  for (int t = 0; t < T; ++t) {
    const int par = t & 1;
    const unsigned short* Ab_ = lds + (ahalf + par) * 8192 + alo;
    const unsigned short* Bb_ = lds + (4 + bhalf + par) * 8192 + bsub;
    short8 af[8], b0, b1;
    // ---- P1: B(t) landed (A(t+1)'s 32 loads stay in flight) ----
    __builtin_amdgcn_sched_barrier(0);
    asm volatile("s_waitcnt vmcnt(32) lgkmcnt(0)" ::: "memory");
    __builtin_amdgcn_s_barrier();
    __builtin_amdgcn_sched_barrier(0);
    STAGEB(t + 1);
#pragma unroll
    for (int mf = 0; mf < 8; ++mf)
      af[mf] = *reinterpret_cast<const short8*>(Ab_ + mf * 1024 + g0);
    b0 = *reinterpret_cast<const short8*>(Bb_ + 0 * 1024 + g0);
    b1 = *reinterpret_cast<const short8*>(Bb_ + 1 * 1024 + g0);
    MFMA16(b0, b1, 0, 1);
    // ---- P2 ----
    b0 = *reinterpret_cast<const short8*>(Bb_ + 2 * 1024 + g0);
    b1 = *reinterpret_cast<const short8*>(Bb_ + 3 * 1024 + g0);
    MFMA16(b0, b1, 2, 3);
    // ---- P3 ----
#pragma unroll
    for (int mf = 0; mf < 8; ++mf)
      af[mf] = *reinterpret_cast<const short8*>(Ab_ + mf * 1024 + g1);
    b0 = *reinterpret_cast<const short8*>(Bb_ + 2 * 1024 + g1);
    b1 = *reinterpret_cast<const short8*>(Bb_ + 3 * 1024 + g1);
    MFMA16(b0, b1, 2, 3);
    // ---- P4: cvt+write A(t+1) (vmcnt(4) leaves B(t+1) flying);
    //          issue A-loads(t+2); finish (kk1, nf 0-1) ----
    __builtin_amdgcn_sched_barrier(0);
    __builtin_amdgcn_s_barrier();
    __builtin_amdgcn_sched_barrier(0);
    asm volatile("s_waitcnt vmcnt(4)" ::: "memory");
    __builtin_amdgcn_sched_barrier(0);
    ACVT(t + 1);
    ALOAD(t + 2);
    b0 = *reinterpret_cast<const short8*>(Bb_ + 0 * 1024 + g1);
    b1 = *reinterpret_cast<const short8*>(Bb_ + 1 * 1024 + g1);
    MFMA16(b0, b1, 0, 1);
  }
#undef STAGEB
#undef ALOAD
#undef ACVT
#undef MFMA16

  // epilogue: C/D layout col=lane&15, row=(lane>>4)*4+reg
#pragma unroll
  for (int mf = 0; mf < 8; ++mf) {
    const int rb = (bm << 8) + wm + mf * 16 + ((lane >> 4) << 2);
#pragma unroll
    for (int nf = 0; nf < 4; ++nf) {
      const int col = (bn << 8) + wn + nf * 16 + (lane & 15);
#pragma unroll
      for (int r = 0; r < 4; ++r)
        Cp[(size_t)(rb + r) * NB + col] = acc[mf][nf][r];
    }
  }
}

// ---- LDS-tiled conv (R9-validated): block = (uo, v-half, 32-n), all 16 co ----
__global__ __launch_bounds__(256) void conv_lds_kernel(
    const float* __restrict__ za, const float* __restrict__ zb,
    const float* __restrict__ zh, const float* __restrict__ w,
    const float* __restrict__ bias, unsigned short* __restrict__ tT) {
  __shared__ float zl[24 * 18 * 32];
  __shared__ float wl[1152];
  __shared__ float bl[16];
  const int b = blockIdx.x;
  const int nt = b & 31, vh = (b >> 5) & 1, uo = b >> 6;
  const int n0 = nt * 32;
  const int tid = threadIdx.x;
#pragma unroll
  for (int it = 0; it < 5; ++it) {
    const int idx = it * 256 + tid;
    if (idx < 1152) wl[idx] = w[idx];
  }
  if (tid < 16) bl[tid] = bias[tid];
  const int nl4 = (tid & 7) * 4;
#pragma unroll
  for (int it = 0; it < 13; ++it) {
    const int R = it * 32 + (tid >> 3);
    if (R < 408) {
      const int ci = R / 51;
      const int rem = R - ci * 51;
      const int kh = rem / 17;
      const int vi = rem - kh * 17;
      const int u = 2 * uo + kh;
      const int v = vh * 16 + vi;
      float4 val = make_float4(0.f, 0.f, 0.f, 0.f);
      if (u < 32 && v < 32) {
        const size_t g = ((size_t)(ci * 1024 + u * 32 + v)) * 1024 + n0 + nl4;
        const float4 a4 = *reinterpret_cast<const float4*>(za + g);
        const float4 b4 = *reinterpret_cast<const float4*>(zb + g);
        val = make_float4(a4.x + b4.x, a4.y + b4.y, a4.z + b4.z, a4.w + b4.w);
      }
      *reinterpret_cast<float4*>(zl + ((ci * 3 + kh) * 18 + vi) * 32 + nl4) = val;
    }
  }
  __syncthreads();
  const int nl = tid & 31;
  const int cop = tid >> 5;
  const float hom = zh[n0 + nl];
  float acc[2][8];
#pragma unroll
  for (int c = 0; c < 2; ++c) {
    const float bb = bl[cop + c * 8] * hom;
#pragma unroll
    for (int vo = 0; vo < 8; ++vo) acc[c][vo] = bb;
  }
  for (int ci = 0; ci < 8; ++ci) {
#pragma unroll
    for (int kh = 0; kh < 3; ++kh) {
      const float* zr = zl + (ci * 3 + kh) * (18 * 32) + nl;
      float zv[17];
#pragma unroll
      for (int vi = 0; vi < 17; ++vi) zv[vi] = zr[vi * 32];
#pragma unroll
      for (int c = 0; c < 2; ++c) {
        const int co = cop + c * 8;
        const float* wp = wl + ((co * 8 + ci) * 3 + kh) * 3;
#pragma unroll
        for (int kw = 0; kw < 3; ++kw) {
          const float wv = wp[kw];
#pragma unroll
          for (int vo = 0; vo < 8; ++vo) acc[c][vo] += wv * zv[2 * vo + kw];
        }
      }
    }
  }
#pragma unroll
  for (int c = 0; c < 2; ++c) {
    const int co = cop + c * 8;
    unsigned short o[8];
#pragma unroll
    for (int vo = 0; vo < 8; ++vo) o[vo] = f2bf(acc[c][vo]);
    uint4 pv;
    pv.x = (unsigned)o[0] | ((unsigned)o[1] << 16);
    pv.y = (unsigned)o[2] | ((unsigned)o[3] << 16);
    pv.z = (unsigned)o[4] | ((unsigned)o[5] << 16);
    pv.w = (unsigned)o[6] | ((unsigned)o[7] << 16);
    *reinterpret_cast<uint4*>(
        tT + (size_t)(n0 + nl) * KP2 + co * 256 + uo * 16 + vh * 8) = pv;
  }
}

// ---- tT rows 4096..4159: hom row + zero pad ----
__global__ __launch_bounds__(256) void homrow_kernel(
    const float* __restrict__ zh, unsigned short* __restrict__ tT) {
  const int n = blockIdx.x * 256 + threadIdx.x;
  unsigned short* p = tT + (size_t)n * KP2 + 4096;
  uint4 z4 = make_uint4(0u, 0u, 0u, 0u);
  uint4 h4 = z4;
  h4.x = (unsigned)f2bf(zh[n]);
  *reinterpret_cast<uint4*>(p) = h4;
#pragma unroll
  for (int i = 1; i < 8; ++i) *reinterpret_cast<uint4*>(p + i * 8) = z4;
}

// ---- final sum of 4 split-K partials -> d_out rows 0..4095 ----
__global__ __launch_bounds__(256) void sum4_kernel(
    const float* __restrict__ p, float* __restrict__ out, int n4) {
  const int i = blockIdx.x * 256 + threadIdx.x;
  if (i >= n4) return;
  const size_t stride4 = (size_t)M2 * NB / 4;
  const float4* p4 = (const float4*)p;
  float4 a = p4[i];
  float4 b = p4[i + stride4];
  float4 c = p4[i + 2 * stride4];
  float4 d = p4[i + 3 * stride4];
  float4 r;
  r.x = (a.x + b.x) + (c.x + d.x);
  r.y = (a.y + b.y) + (c.y + d.y);
  r.z = (a.z + b.z) + (c.z + d.z);
  r.w = (a.w + b.w) + (c.w + d.w);
  reinterpret_cast<float4*>(out)[i] = r;
}

// ---- out row 4096: wave-per-column dot over f32 A row x bf16 tT ----
__global__ __launch_bounds__(256) void outrow_kernel(
    const float* __restrict__ Arow, const unsigned short* __restrict__ tT,
    float* __restrict__ out) {
  const int wid = threadIdx.x >> 6, lane = threadIdx.x & 63;
  const int n = blockIdx.x * 4 + wid;
  const unsigned short* trow = tT + (size_t)n * KP2;
  float acc = 0.f;
  for (int i = lane; i < OUT_DIM; i += 64) acc += Arow[i] * bf2f(trow[i]);
#pragma unroll
  for (int m = 1; m <= 32; m <<= 1) acc += __shfl_xor(acc, m);
  if (lane == 0) out[(size_t)4096 * NB + n] = acc;
}

extern "C" void kernel_launch(void* const* d_in, const int* in_sizes, int n_in,
                              void* d_out, int out_size, void* d_ws, size_t ws_size,
                              hipStream_t stream) {
  const float* w    = (const float*)d_in[0];  // (16,8,3,3)
  const float* bias = (const float*)d_in[1];  // (16,)
  const float* A    = (const float*)d_in[2];  // (4097,4097)
  const float* Ainv = (const float*)d_in[3];  // (8193,8193)
  const float* x    = (const float*)d_in[4];  // (8193,1024)
  float* out = (float*)d_out;                 // (4097,1024)

  // Workspace (~160 MB): xT_b 16.9 | z2 67.1 | tT_b 8.5 | zh 4KB | outp 67.1
  char* ws = (char*)d_ws;
  const size_t o_z2 = (size_t)NB * KP1 * 2;
  const size_t o_tT = o_z2 + (size_t)2 * M1 * NB * 4;
  const size_t o_zh = o_tT + (size_t)NB * KP2 * 2;
  const size_t o_op = o_zh + 4096;
  unsigned short* xT_b = (unsigned short*)ws;
  float*          z2   = (float*)(ws + o_z2);
  unsigned short* tT_b = (unsigned short*)(ws + o_tT);
  float*          zh   = (float*)(ws + o_zh);
  float*          outp = (float*)(ws + o_op);
  (void)ws_size; (void)in_sizes; (void)n_in; (void)out_size;

  hipFuncSetAttribute((const void*)gemm_fa<129, 2, 2, M1>,
                      hipFuncAttributeMaxDynamicSharedMemorySize, 131072);
  hipFuncSetAttribute((const void*)gemm_fa<65, 4, 1, M2>,
                      hipFuncAttributeMaxDynamicSharedMemorySize, 131072);

  // 1) zero zh
  zero_kernel<<<1, 256, 0, stream>>>((float4*)zh, 256);
  // 2) x -> x^T bf16 + fused zh = Ainv[8192,:] @ x
  transpose_cvt_zh_kernel<<<(KP1 / 32) * (NB / 32), 256, 0, stream>>>(
      x, xT_b, Ainv + (size_t)8192 * IN_DIM, zh, IN_DIM, NB, KP1);
  // 3) z{a,b} = Ainv @ x  (fused-A 4-phase GEMM, exactly 256 blocks)
  gemm_fa<129, 2, 2, M1><<<256, 512, 131072, stream>>>(
      Ainv, xT_b, z2, IN_DIM, KP1);
  // 4) t^T rows 0..4095 = conv(za+zb, hom=zh)
  conv_lds_kernel<<<1024, 256, 0, stream>>>(
      z2, z2 + (size_t)M1 * NB, zh, w, bias, tT_b);
  // 5) t^T rows 4096..4159 = hom + zero pad
  homrow_kernel<<<4, 256, 0, stream>>>(zh, tT_b);
  // 6) outp[0..3] = A @ t  (fused-A 4-phase GEMM, exactly 256 blocks)
  gemm_fa<65, 4, 1, M2><<<256, 512, 131072, stream>>>(
      A, tT_b, outp, OUT_DIM, KP2);
  // 7) out rows 0..4095 = sum of partials
  sum4_kernel<<<(M2 * NB / 4) / 256, 256, 0, stream>>>(
      outp, out, M2 * NB / 4);
  // 8) out row 4096 = A[4096,:] @ t
  outrow_kernel<<<NB / 4, 256, 0, stream>>>(
      A + (size_t)4096 * OUT_DIM, tT_b, out);
}

// Round 12
// 536.797 us; speedup vs baseline: 1.2690x; 1.2690x over previous
//
#include <hip/hip_runtime.h>

// ---- problem dims ----
#define IN_DIM 8193
#define OUT_DIM 4097
#define NB 1024
#define M1 8192    // GEMM1 M (rows 0..8191; row 8192 = hom handled separately)
#define KP1 8256   // 129 * 64 (B-side padded K)
#define M2 4096    // GEMM2 M (row 4096 handled separately)
#define KP2 4160   // 65 * 64

typedef __attribute__((ext_vector_type(8))) short short8;
typedef __attribute__((ext_vector_type(4))) float f32x4;

__device__ __forceinline__ unsigned short f2bf(float f) {
  unsigned int u = __float_as_uint(f);
  u = (u + 0x7fffu + ((u >> 16) & 1u)) >> 16;  // RNE
  return (unsigned short)u;
}
__device__ __forceinline__ float bf2f(unsigned short u) {
  return __uint_as_float(((unsigned int)u) << 16);
}

// ---- transpose+convert x -> xT bf16, FUSED hom row: zh[n] += Ainv[8192,:]·x[:,n] ----
__global__ __launch_bounds__(256) void transpose_cvt_zh_kernel(
    const float* __restrict__ src, unsigned short* __restrict__ dst,
    const float* __restrict__ arow, float* __restrict__ zh,
    int K, int N, int Kp) {
  __shared__ float tl[32][33];
  const int ntk = Kp >> 5;
  int bx = blockIdx.x % ntk;
  int by = blockIdx.x / ntk;
  int k0 = bx * 32, n0 = by * 32;
  int tx = threadIdx.x & 31, ty = threadIdx.x >> 5;
#pragma unroll
  for (int i = 0; i < 4; ++i) {
    int k = k0 + ty + i * 8;
    tl[ty + i * 8][tx] = (k < K) ? src[(size_t)k * N + n0 + tx] : 0.f;
  }
  const float av = (k0 + tx < K) ? arow[k0 + tx] : 0.f;
  __syncthreads();
#pragma unroll
  for (int i = 0; i < 4; ++i) {
    int n = n0 + ty + i * 8;
    float v = tl[tx][ty + i * 8];
    dst[(size_t)n * Kp + k0 + tx] = f2bf(v);
    float c = av * v;
#pragma unroll
    for (int m = 1; m <= 16; m <<= 1) c += __shfl_xor(c, m);
    if (tx == 0) atomicAdd(&zh[n], c);
  }
}

// ---- float4 zero ----
__global__ __launch_bounds__(256) void zero_kernel(float4* __restrict__ p, int n) {
  int i = blockIdx.x * 256 + threadIdx.x;
  if (i < n) p[i] = make_float4(0.f, 0.f, 0.f, 0.f);
}

// 8 loads from 4 row-pointers (offsets 0,4): per-instruction lanes sweep the
// col-pair index -> 8B stride within a row -> ~8 cache lines/instr (R11's
// scalar layout was 64 lines/instr -> TA serialization, MfmaUtil 13%).
// "=&v" early-clobber is load-bearing (R10 crash: output aliased addr pair).
#define ALOADBLK(R0, R1, R2, R3, R4, R5, R6, R7, P0, P1, P2, P3)              \
  asm volatile("global_load_dword %0, %8, off\n\t"                            \
               "global_load_dword %1, %8, off offset:4\n\t"                   \
               "global_load_dword %2, %9, off\n\t"                            \
               "global_load_dword %3, %9, off offset:4\n\t"                   \
               "global_load_dword %4, %10, off\n\t"                           \
               "global_load_dword %5, %10, off offset:4\n\t"                  \
               "global_load_dword %6, %11, off\n\t"                           \
               "global_load_dword %7, %11, off offset:4\n\t"                  \
               : "=&v"(R0), "=&v"(R1), "=&v"(R2), "=&v"(R3), "=&v"(R4),       \
                 "=&v"(R5), "=&v"(R6), "=&v"(R7)                              \
               : "v"(P0), "v"(P1), "v"(P2), "v"(P3))

// ---- Fused-A 4-phase pipelined GEMM, exact 256-block grid ----
// Cpart(sp) (MROWS x NB) = f32A(256-tile bm, cvt->bf16 in staging)
//                          * Bt(256-tile bn, bf16 padded)^T over kt range.
// Tile 256x256, BK=64, 8 waves (2M x 4N), per-wave 128x64.
// A-staging: thread=(prow=tid>>5, pcol=tid&31); 16 rounds x (2 coalesced
// dword loads of cols 2p,2p+1 in row prow+16*rnd); cvt via v_cvt_pk_bf16_f32
// (1 instr/pair); ds_write_b32 from ONE base reg + compile-time offset
// ((rnd&7)*2048 + (rnd>>3)*32768; swizzle XOR is rnd-invariant mod 8).
// vmcnt ledger unchanged from R11 (A still 32 loads/thread):
//   P1(t): vmcnt(32) drains B(t)'s 4, keeps A(t+1)'s 32 flying
//   P4(t): vmcnt(4) drains A(t+1)'s 32, keeps B(t+1)'s 4; ACVT; ALOAD(t+2)
// No A zero-guards: B's padded cols are zero (garbage*0=0); all A reads
// provably in-bounds for both GEMMs.
template <int NKT, int NSPLIT, int BMBITS, int MROWS>
__global__ __launch_bounds__(512) void gemm_fa(
    const float* __restrict__ Af,
    const unsigned short* __restrict__ Bt,
    float* __restrict__ C, int Kact, int Kp) {
  extern __shared__ unsigned short lds[];  // 8 * 8192 shorts = 128 KB
  const int tid = threadIdx.x;
  const int wid = tid >> 6;
  const int lane = tid & 63;
  const int b = blockIdx.x;
  const int x = b & 7, q = b >> 3;
  const int bm = (q & ((1 << BMBITS) - 1)) * 8 + x;
  const int bn = (q >> BMBITS) & 3;
  const int sp = q >> (BMBITS + 2);
  const int wm = (wid >> 2) << 7;  // 0 / 128
  const int wn = (wid & 3) << 6;   // 0 / 64 / 128 / 192

  const int qk = NKT / NSPLIT, rrk = NKT % NSPLIT;
  const int kt0 = sp * qk + (sp < rrk ? sp : rrk);
  const int T = qk + (sp < rrk ? 1 : 0);
  float* Cp = C + (size_t)sp * MROWS * NB;

  // fragment-read geometry (R7/R8-validated)
  const int g0 = ((lane >> 4) ^ (lane & 7)) * 8;        // kk=0
  const int g1 = ((4 + (lane >> 4)) ^ (lane & 7)) * 8;  // kk=1
  const int alo = (lane & 15) * 64;
  const int bhalf = (wn >> 7) << 1;
  const int ahalf = (wid >> 2) << 1;
  const int bsub = ((wn & 64) << 6) + alo;

  // A-staging geometry
  const int prow = tid >> 5;   // 0..15
  const int pcol = tid & 31;   // col pair index (cols 2p, 2p+1)
  // LDS byte base for A writes (parity/round added per use):
  const int abase0 =
      prow * 128 + (((pcol >> 2) ^ (prow & 7)) << 4) + ((pcol & 3) << 2);
  const size_t rs16 = (size_t)Kact << 4;  // 16 rows of floats

#define STAGEB(TT)                                                             \
  do {                                                                         \
    const int tt_ = (TT);                                                      \
    const int kc_ = kt0 + (tt_ < T - 1 ? tt_ : T - 1);                         \
    const int par_ = tt_ & 1;                                                  \
    _Pragma("unroll")                                                          \
    for (int h_ = 0; h_ < 2; ++h_) {                                           \
      _Pragma("unroll")                                                        \
      for (int L_ = 0; L_ < 2; ++L_) {                                         \
        const int s_ = L_ * 512 + tid;                                         \
        const int row_ = s_ >> 3;                                              \
        const int gl_ = (s_ & 7) ^ (row_ & 7);                                 \
        const unsigned short* g_ =                                             \
            Bt + (size_t)((bn << 8) + (h_ << 7) + row_) * Kp + (kc_ << 6) +    \
            gl_ * 8;                                                           \
        unsigned short* l_ = lds + (4 + (h_ << 1) + par_) * 8192 +             \
                             (size_t)(L_ * 512 + wid * 64) * 8;                \
        __builtin_amdgcn_global_load_lds(                                      \
            (const __attribute__((address_space(1))) void*)g_,                 \
            (__attribute__((address_space(3))) void*)l_, 16, 0, 0);            \
      }                                                                        \
    }                                                                          \
  } while (0)

#define ALOAD(TT)                                                              \
  do {                                                                         \
    const int tt_ = (TT);                                                      \
    const int kc_ = kt0 + (tt_ < T - 1 ? tt_ : T - 1);                         \
    const float* q0_ =                                                         \
        Af + (size_t)((bm << 8) + prow) * Kact + (kc_ << 6) + (pcol << 1);     \
    ALOADBLK(ar[0], ar[1], ar[2], ar[3], ar[4], ar[5], ar[6], ar[7],           \
             q0_, q0_ + rs16, q0_ + rs16 * 2, q0_ + rs16 * 3);                 \
    ALOADBLK(ar[8], ar[9], ar[10], ar[11], ar[12], ar[13], ar[14], ar[15],     \
             q0_ + rs16 * 4, q0_ + rs16 * 5, q0_ + rs16 * 6, q0_ + rs16 * 7);  \
    ALOADBLK(ar[16], ar[17], ar[18], ar[19], ar[20], ar[21], ar[22], ar[23],   \
             q0_ + rs16 * 8, q0_ + rs16 * 9, q0_ + rs16 * 10,                  \
             q0_ + rs16 * 11);                                                 \
    ALOADBLK(ar[24], ar[25], ar[26], ar[27], ar[28], ar[29], ar[30], ar[31],   \
             q0_ + rs16 * 12, q0_ + rs16 * 13, q0_ + rs16 * 14,                \
             q0_ + rs16 * 15);                                                 \
  } while (0)

#define ACVT(TT)                                                               \
  do {                                                                         \
    const int parw_ = (TT) & 1;                                                \
    char* wb_ = (char*)lds + abase0 + (parw_ << 14);                           \
    _Pragma("unroll")                                                          \
    for (int r_ = 0; r_ < 16; ++r_) {                                          \
      unsigned pk_;                                                            \
      asm volatile("v_cvt_pk_bf16_f32 %0, %1, %2"                              \
                   : "=v"(pk_) : "v"(ar[2 * r_]), "v"(ar[2 * r_ + 1]));        \
      *reinterpret_cast<unsigned*>(wb_ + ((r_ & 7) * 2048 +                    \
                                          (r_ >> 3) * 32768)) = pk_;           \
    }                                                                          \
  } while (0)

#define MFMA16(BV0, BV1, NF0, NF1)                                             \
  do {                                                                         \
    __builtin_amdgcn_s_setprio(1);                                             \
    _Pragma("unroll")                                                          \
    for (int mf_ = 0; mf_ < 8; ++mf_) {                                        \
      asm volatile("v_mfma_f32_16x16x32_bf16 %0, %1, %2, %0"                   \
                   : "+v"(acc[mf_][NF0]) : "v"(af[mf_]), "v"(BV0));            \
      asm volatile("v_mfma_f32_16x16x32_bf16 %0, %1, %2, %0"                   \
                   : "+v"(acc[mf_][NF1]) : "v"(af[mf_]), "v"(BV1));            \
    }                                                                          \
    __builtin_amdgcn_s_setprio(0);                                             \
  } while (0)

  f32x4 acc[8][4];
#pragma unroll
  for (int i = 0; i < 8; ++i)
#pragma unroll
    for (int j = 0; j < 4; ++j) acc[i][j] = (f32x4)(0.0f);

  float ar[32];
  // prologue: A(0) load+cvt+write; B(0) issue; A(1) loads in flight
  ALOAD(0);
  __builtin_amdgcn_sched_barrier(0);
  asm volatile("s_waitcnt vmcnt(0)" ::: "memory");
  __builtin_amdgcn_sched_barrier(0);
  ACVT(0);
  __builtin_amdgcn_sched_barrier(0);
  STAGEB(0);
  __builtin_amdgcn_sched_barrier(0);
  ALOAD(1);
  __builtin_amdgcn_sched_barrier(0);

  for (int t = 0; t < T; ++t) {
    const int par = t & 1;
    const unsigned short* Ab_ = lds + (ahalf + par) * 8192 + alo;
    const unsigned short* Bb_ = lds + (4 + bhalf + par) * 8192 + bsub;
    short8 af[8], b0, b1;
    // ---- P1: B(t) landed (A(t+1)'s 32 loads stay in flight) ----
    __builtin_amdgcn_sched_barrier(0);
    asm volatile("s_waitcnt vmcnt(32) lgkmcnt(0)" ::: "memory");
    __builtin_amdgcn_s_barrier();
    __builtin_amdgcn_sched_barrier(0);
    STAGEB(t + 1);
#pragma unroll
    for (int mf = 0; mf < 8; ++mf)
      af[mf] = *reinterpret_cast<const short8*>(Ab_ + mf * 1024 + g0);
    b0 = *reinterpret_cast<const short8*>(Bb_ + 0 * 1024 + g0);
    b1 = *reinterpret_cast<const short8*>(Bb_ + 1 * 1024 + g0);
    MFMA16(b0, b1, 0, 1);
    // ---- P2 ----
    b0 = *reinterpret_cast<const short8*>(Bb_ + 2 * 1024 + g0);
    b1 = *reinterpret_cast<const short8*>(Bb_ + 3 * 1024 + g0);
    MFMA16(b0, b1, 2, 3);
    // ---- P3 ----
#pragma unroll
    for (int mf = 0; mf < 8; ++mf)
      af[mf] = *reinterpret_cast<const short8*>(Ab_ + mf * 1024 + g1);
    b0 = *reinterpret_cast<const short8*>(Bb_ + 2 * 1024 + g1);
    b1 = *reinterpret_cast<const short8*>(Bb_ + 3 * 1024 + g1);
    MFMA16(b0, b1, 2, 3);
    // ---- P4: cvt+write A(t+1) (vmcnt(4) leaves B(t+1) flying);
    //          issue A-loads(t+2); finish (kk1, nf 0-1) ----
    __builtin_amdgcn_sched_barrier(0);
    __builtin_amdgcn_s_barrier();
    __builtin_amdgcn_sched_barrier(0);
    asm volatile("s_waitcnt vmcnt(4)" ::: "memory");
    __builtin_amdgcn_sched_barrier(0);
    ACVT(t + 1);
    ALOAD(t + 2);
    b0 = *reinterpret_cast<const short8*>(Bb_ + 0 * 1024 + g1);
    b1 = *reinterpret_cast<const short8*>(Bb_ + 1 * 1024 + g1);
    MFMA16(b0, b1, 0, 1);
  }
#undef STAGEB
#undef ALOAD
#undef ACVT
#undef MFMA16

  // epilogue: C/D layout col=lane&15, row=(lane>>4)*4+reg
#pragma unroll
  for (int mf = 0; mf < 8; ++mf) {
    const int rb = (bm << 8) + wm + mf * 16 + ((lane >> 4) << 2);
#pragma unroll
    for (int nf = 0; nf < 4; ++nf) {
      const int col = (bn << 8) + wn + nf * 16 + (lane & 15);
#pragma unroll
      for (int r = 0; r < 4; ++r)
        Cp[(size_t)(rb + r) * NB + col] = acc[mf][nf][r];
    }
  }
}

// ---- LDS-tiled conv (R9-validated): block = (uo, v-half, 32-n), all 16 co ----
__global__ __launch_bounds__(256) void conv_lds_kernel(
    const float* __restrict__ za, const float* __restrict__ zb,
    const float* __restrict__ zh, const float* __restrict__ w,
    const float* __restrict__ bias, unsigned short* __restrict__ tT) {
  __shared__ float zl[24 * 18 * 32];
  __shared__ float wl[1152];
  __shared__ float bl[16];
  const int b = blockIdx.x;
  const int nt = b & 31, vh = (b >> 5) & 1, uo = b >> 6;
  const int n0 = nt * 32;
  const int tid = threadIdx.x;
#pragma unroll
  for (int it = 0; it < 5; ++it) {
    const int idx = it * 256 + tid;
    if (idx < 1152) wl[idx] = w[idx];
  }
  if (tid < 16) bl[tid] = bias[tid];
  const int nl4 = (tid & 7) * 4;
#pragma unroll
  for (int it = 0; it < 13; ++it) {
    const int R = it * 32 + (tid >> 3);
    if (R < 408) {
      const int ci = R / 51;
      const int rem = R - ci * 51;
      const int kh = rem / 17;
      const int vi = rem - kh * 17;
      const int u = 2 * uo + kh;
      const int v = vh * 16 + vi;
      float4 val = make_float4(0.f, 0.f, 0.f, 0.f);
      if (u < 32 && v < 32) {
        const size_t g = ((size_t)(ci * 1024 + u * 32 + v)) * 1024 + n0 + nl4;
        const float4 a4 = *reinterpret_cast<const float4*>(za + g);
        const float4 b4 = *reinterpret_cast<const float4*>(zb + g);
        val = make_float4(a4.x + b4.x, a4.y + b4.y, a4.z + b4.z, a4.w + b4.w);
      }
      *reinterpret_cast<float4*>(zl + ((ci * 3 + kh) * 18 + vi) * 32 + nl4) = val;
    }
  }
  __syncthreads();
  const int nl = tid & 31;
  const int cop = tid >> 5;
  const float hom = zh[n0 + nl];
  float acc[2][8];
#pragma unroll
  for (int c = 0; c < 2; ++c) {
    const float bb = bl[cop + c * 8] * hom;
#pragma unroll
    for (int vo = 0; vo < 8; ++vo) acc[c][vo] = bb;
  }
  for (int ci = 0; ci < 8; ++ci) {
#pragma unroll
    for (int kh = 0; kh < 3; ++kh) {
      const float* zr = zl + (ci * 3 + kh) * (18 * 32) + nl;
      float zv[17];
#pragma unroll
      for (int vi = 0; vi < 17; ++vi) zv[vi] = zr[vi * 32];
#pragma unroll
      for (int c = 0; c < 2; ++c) {
        const int co = cop + c * 8;
        const float* wp = wl + ((co * 8 + ci) * 3 + kh) * 3;
#pragma unroll
        for (int kw = 0; kw < 3; ++kw) {
          const float wv = wp[kw];
#pragma unroll
          for (int vo = 0; vo < 8; ++vo) acc[c][vo] += wv * zv[2 * vo + kw];
        }
      }
    }
  }
#pragma unroll
  for (int c = 0; c < 2; ++c) {
    const int co = cop + c * 8;
    unsigned short o[8];
#pragma unroll
    for (int vo = 0; vo < 8; ++vo) o[vo] = f2bf(acc[c][vo]);
    uint4 pv;
    pv.x = (unsigned)o[0] | ((unsigned)o[1] << 16);
    pv.y = (unsigned)o[2] | ((unsigned)o[3] << 16);
    pv.z = (unsigned)o[4] | ((unsigned)o[5] << 16);
    pv.w = (unsigned)o[6] | ((unsigned)o[7] << 16);
    *reinterpret_cast<uint4*>(
        tT + (size_t)(n0 + nl) * KP2 + co * 256 + uo * 16 + vh * 8) = pv;
  }
}

// ---- tT rows 4096..4159: hom row + zero pad ----
__global__ __launch_bounds__(256) void homrow_kernel(
    const float* __restrict__ zh, unsigned short* __restrict__ tT) {
  const int n = blockIdx.x * 256 + threadIdx.x;
  unsigned short* p = tT + (size_t)n * KP2 + 4096;
  uint4 z4 = make_uint4(0u, 0u, 0u, 0u);
  uint4 h4 = z4;
  h4.x = (unsigned)f2bf(zh[n]);
  *reinterpret_cast<uint4*>(p) = h4;
#pragma unroll
  for (int i = 1; i < 8; ++i) *reinterpret_cast<uint4*>(p + i * 8) = z4;
}

// ---- final sum of 4 split-K partials -> d_out rows 0..4095 ----
__global__ __launch_bounds__(256) void sum4_kernel(
    const float* __restrict__ p, float* __restrict__ out, int n4) {
  const int i = blockIdx.x * 256 + threadIdx.x;
  if (i >= n4) return;
  const size_t stride4 = (size_t)M2 * NB / 4;
  const float4* p4 = (const float4*)p;
  float4 a = p4[i];
  float4 b = p4[i + stride4];
  float4 c = p4[i + 2 * stride4];
  float4 d = p4[i + 3 * stride4];
  float4 r;
  r.x = (a.x + b.x) + (c.x + d.x);
  r.y = (a.y + b.y) + (c.y + d.y);
  r.z = (a.z + b.z) + (c.z + d.z);
  r.w = (a.w + b.w) + (c.w + d.w);
  reinterpret_cast<float4*>(out)[i] = r;
}

// ---- out row 4096: wave-per-column dot over f32 A row x bf16 tT ----
__global__ __launch_bounds__(256) void outrow_kernel(
    const float* __restrict__ Arow, const unsigned short* __restrict__ tT,
    float* __restrict__ out) {
  const int wid = threadIdx.x >> 6, lane = threadIdx.x & 63;
  const int n = blockIdx.x * 4 + wid;
  const unsigned short* trow = tT + (size_t)n * KP2;
  float acc = 0.f;
  for (int i = lane; i < OUT_DIM; i += 64) acc += Arow[i] * bf2f(trow[i]);
#pragma unroll
  for (int m = 1; m <= 32; m <<= 1) acc += __shfl_xor(acc, m);
  if (lane == 0) out[(size_t)4096 * NB + n] = acc;
}

extern "C" void kernel_launch(void* const* d_in, const int* in_sizes, int n_in,
                              void* d_out, int out_size, void* d_ws, size_t ws_size,
                              hipStream_t stream) {
  const float* w    = (const float*)d_in[0];  // (16,8,3,3)
  const float* bias = (const float*)d_in[1];  // (16,)
  const float* A    = (const float*)d_in[2];  // (4097,4097)
  const float* Ainv = (const float*)d_in[3];  // (8193,8193)
  const float* x    = (const float*)d_in[4];  // (8193,1024)
  float* out = (float*)d_out;                 // (4097,1024)

  // Workspace (~160 MB): xT_b 16.9 | z2 67.1 | tT_b 8.5 | zh 4KB | outp 67.1
  char* ws = (char*)d_ws;
  const size_t o_z2 = (size_t)NB * KP1 * 2;
  const size_t o_tT = o_z2 + (size_t)2 * M1 * NB * 4;
  const size_t o_zh = o_tT + (size_t)NB * KP2 * 2;
  const size_t o_op = o_zh + 4096;
  unsigned short* xT_b = (unsigned short*)ws;
  float*          z2   = (float*)(ws + o_z2);
  unsigned short* tT_b = (unsigned short*)(ws + o_tT);
  float*          zh   = (float*)(ws + o_zh);
  float*          outp = (float*)(ws + o_op);
  (void)ws_size; (void)in_sizes; (void)n_in; (void)out_size;

  hipFuncSetAttribute((const void*)gemm_fa<129, 2, 2, M1>,
                      hipFuncAttributeMaxDynamicSharedMemorySize, 131072);
  hipFuncSetAttribute((const void*)gemm_fa<65, 4, 1, M2>,
                      hipFuncAttributeMaxDynamicSharedMemorySize, 131072);

  // 1) zero zh
  zero_kernel<<<1, 256, 0, stream>>>((float4*)zh, 256);
  // 2) x -> x^T bf16 + fused zh = Ainv[8192,:] @ x
  transpose_cvt_zh_kernel<<<(KP1 / 32) * (NB / 32), 256, 0, stream>>>(
      x, xT_b, Ainv + (size_t)8192 * IN_DIM, zh, IN_DIM, NB, KP1);
  // 3) z{a,b} = Ainv @ x  (fused-A 4-phase GEMM, exactly 256 blocks)
  gemm_fa<129, 2, 2, M1><<<256, 512, 131072, stream>>>(
      Ainv, xT_b, z2, IN_DIM, KP1);
  // 4) t^T rows 0..4095 = conv(za+zb, hom=zh)
  conv_lds_kernel<<<1024, 256, 0, stream>>>(
      z2, z2 + (size_t)M1 * NB, zh, w, bias, tT_b);
  // 5) t^T rows 4096..4159 = hom + zero pad
  homrow_kernel<<<4, 256, 0, stream>>>(zh, tT_b);
  // 6) outp[0..3] = A @ t  (fused-A 4-phase GEMM, exactly 256 blocks)
  gemm_fa<65, 4, 1, M2><<<256, 512, 131072, stream>>>(
      A, tT_b, outp, OUT_DIM, KP2);
  // 7) out rows 0..4095 = sum of partials
  sum4_kernel<<<(M2 * NB / 4) / 256, 256, 0, stream>>>(
      outp, out, M2 * NB / 4);
  // 8) out row 4096 = A[4096,:] @ t
  outrow_kernel<<<NB / 4, 256, 0, stream>>>(
      A + (size_t)4096 * OUT_DIM, tT_b, out);
}

// Round 13
// 431.849 us; speedup vs baseline: 1.5774x; 1.2430x over previous
//
#include <hip/hip_runtime.h>

// ---- problem dims ----
#define IN_DIM 8193
#define OUT_DIM 4097
#define NB 1024
#define M1 8192    // GEMM1 M (rows 0..8191; row 8192 = hom handled separately)
#define KP1 8256   // 129 * 64
#define M2 4096    // GEMM2 M (row 4096 handled separately)
#define KP2 4160   // 65 * 64

typedef __attribute__((ext_vector_type(8))) short short8;
typedef __attribute__((ext_vector_type(4))) float f32x4;

__device__ __forceinline__ unsigned short f2bf(float f) {
  unsigned int u = __float_as_uint(f);
  u = (u + 0x7fffu + ((u >> 16) & 1u)) >> 16;  // RNE
  return (unsigned short)u;
}
__device__ __forceinline__ float bf2f(unsigned short u) {
  return __uint_as_float(((unsigned int)u) << 16);
}

// ---- pad + f32->bf16 convert (row-major -> row-major padded) ----
__global__ __launch_bounds__(256) void cvt_pad_kernel(
    const float* __restrict__ src, unsigned short* __restrict__ dst,
    int sR, int sC, int dR, int dC) {
  int gid = blockIdx.x * 256 + threadIdx.x;
  int i4 = gid * 4;
  if (i4 >= dR * dC) return;
  int r = i4 / dC;
  int c = i4 - r * dC;
  unsigned short o[4];
#pragma unroll
  for (int j = 0; j < 4; ++j) {
    int cc = c + j;
    float v = (r < sR && cc < sC) ? src[(size_t)r * sC + cc] : 0.f;
    o[j] = f2bf(v);
  }
  unsigned int lo = (unsigned)o[0] | ((unsigned)o[1] << 16);
  unsigned int hi = (unsigned)o[2] | ((unsigned)o[3] << 16);
  *reinterpret_cast<uint2*>(dst + i4) = make_uint2(lo, hi);
}

// ---- transpose+convert x -> xT bf16, FUSED hom row: zh[n] += Ainv[8192,:]·x[:,n] ----
__global__ __launch_bounds__(256) void transpose_cvt_zh_kernel(
    const float* __restrict__ src, unsigned short* __restrict__ dst,
    const float* __restrict__ arow, float* __restrict__ zh,
    int K, int N, int Kp) {
  __shared__ float tl[32][33];
  const int ntk = Kp >> 5;
  int bx = blockIdx.x % ntk;
  int by = blockIdx.x / ntk;
  int k0 = bx * 32, n0 = by * 32;
  int tx = threadIdx.x & 31, ty = threadIdx.x >> 5;
#pragma unroll
  for (int i = 0; i < 4; ++i) {
    int k = k0 + ty + i * 8;
    tl[ty + i * 8][tx] = (k < K) ? src[(size_t)k * N + n0 + tx] : 0.f;
  }
  const float av = (k0 + tx < K) ? arow[k0 + tx] : 0.f;
  __syncthreads();
#pragma unroll
  for (int i = 0; i < 4; ++i) {
    int n = n0 + ty + i * 8;
    float v = tl[tx][ty + i * 8];
    dst[(size_t)n * Kp + k0 + tx] = f2bf(v);
    float c = av * v;
#pragma unroll
    for (int m = 1; m <= 16; m <<= 1) c += __shfl_xor(c, m);
    if (tx == 0) atomicAdd(&zh[n], c);
  }
}

// ---- float4 zero ----
__global__ __launch_bounds__(256) void zero_kernel(float4* __restrict__ p, int n) {
  int i = blockIdx.x * 256 + threadIdx.x;
  if (i < n) p[i] = make_float4(0.f, 0.f, 0.f, 0.f);
}

// ---- 8-barrier 4-phase pipelined GEMM (m201 phase discipline), 256 blocks ----
// Cpart(sp) (MROWS x NB) = A(256-tile bm) * Bt(256-tile bn)^T over kt range.
// Tile 256x256, BK=64, 8 waves (2M x 4N), per-wave 128x64.
// LDS = 8 half-slots x 16KB (A/B x half x parity). Per K-tile, 4 quadrant
// phases, each {stage half-tile; ds_reads; s_barrier; lgkmcnt(0);
// sched_barrier; setprio MFMA x16; s_barrier}:
//   Ph1: stage B(t+1)h0;  A-kk0(8)+B01-kk0(2);  MFMA (kk0, nf0-1)
//   Ph2: stage B(t+1)h1;  B23-kk0(2);           MFMA (kk0, nf2-3)
//   Ph3: (no stage)       A-kk1(8)+B23-kk1(2);  MFMA (kk1, nf2-3)
//   Ph4: stage A(t+2)h0+h1; B01-kk1(2); vmcnt(4); MFMA (kk1, nf0-1)
// Hazards: B(t+1) slots (parity^1) dead since Ph4(t-1) lgkm0+barrier;
// A(t+2) slots (parity t&1) dead after Ph3(t) lgkm0+barrier. vmcnt ledger
// (issue order B(t+1):2+2, A(t+2):4): vmcnt(4) at Ph4 drains A(t+1)+B(t+1),
// keeps A(t+2)'s 4 flying — counted, never 0.
// Mapping: x=b&7 (XCD), bm=(q&((1<<BMBITS)-1))*8+x — all bn-blocks of one
// A-panel co-resident on one XCD (R8-validated, FETCH ~= ideal).
template <int NKT, int NSPLIT, int BMBITS, int MROWS>
__global__ __launch_bounds__(512) void gemm_dp(
    const unsigned short* __restrict__ Ab,
    const unsigned short* __restrict__ Bt,
    float* __restrict__ C, int Kp) {
  extern __shared__ unsigned short lds[];  // 8 * 8192 shorts = 128 KB
  const int tid = threadIdx.x;
  const int wid = tid >> 6;
  const int lane = tid & 63;
  const int b = blockIdx.x;
  const int x = b & 7, q = b >> 3;
  const int bm = (q & ((1 << BMBITS) - 1)) * 8 + x;
  const int bn = (q >> BMBITS) & 3;
  const int sp = q >> (BMBITS + 2);
  const int wm = (wid >> 2) << 7;  // 0 / 128
  const int wn = (wid & 3) << 6;   // 0 / 64 / 128 / 192

  const int qk = NKT / NSPLIT, rrk = NKT % NSPLIT;
  const int kt0 = sp * qk + (sp < rrk ? sp : rrk);
  const int T = qk + (sp < rrk ? 1 : 0);
  float* Cp = C + (size_t)sp * MROWS * NB;

  // fragment-read geometry (R7/R8/R9-validated)
  const int g0 = ((lane >> 4) ^ (lane & 7)) * 8;        // kk=0
  const int g1 = ((4 + (lane >> 4)) ^ (lane & 7)) * 8;  // kk=1
  const int alo = (lane & 15) * 64;
  const int bhalf = (wn >> 7) << 1;
  const int ahalf = (wid >> 2) << 1;
  const int bsub = ((wn & 64) << 6) + alo;

// stage ONE half-tile (2 x global_load_lds) for tile TT, matrix ISA, half H
#define STAGEH(TT, ISA, H)                                                     \
  do {                                                                         \
    const int tt_ = (TT);                                                      \
    const int kc_ = kt0 + (tt_ < T - 1 ? tt_ : T - 1);                         \
    const int par_ = tt_ & 1;                                                  \
    const unsigned short* M_ = (ISA) ? Ab : Bt;                                \
    const int br_ = ((ISA) ? bm : bn) << 8;                                    \
    _Pragma("unroll")                                                          \
    for (int L_ = 0; L_ < 2; ++L_) {                                           \
      const int s_ = L_ * 512 + tid;                                           \
      const int row_ = s_ >> 3;                                                \
      const int gl_ = (s_ & 7) ^ (row_ & 7);                                   \
      const unsigned short* g_ = M_ + (size_t)(br_ + ((H) << 7) + row_) * Kp   \
                                    + (kc_ << 6) + gl_ * 8;                    \
      unsigned short* l_ = lds + (((ISA) ? 0 : 4) + ((H) << 1) + par_) * 8192  \
                               + (size_t)(L_ * 512 + wid * 64) * 8;            \
      __builtin_amdgcn_global_load_lds(                                        \
          (const __attribute__((address_space(1))) void*)g_,                   \
          (__attribute__((address_space(3))) void*)l_, 16, 0, 0);              \
    }                                                                          \
  } while (0)

#define MFMA16(BV0, BV1, NF0, NF1)                                             \
  do {                                                                         \
    __builtin_amdgcn_s_setprio(1);                                             \
    _Pragma("unroll")                                                          \
    for (int mf_ = 0; mf_ < 8; ++mf_) {                                        \
      asm volatile("v_mfma_f32_16x16x32_bf16 %0, %1, %2, %0"                   \
                   : "+v"(acc[mf_][NF0]) : "v"(af[mf_]), "v"(BV0));            \
      asm volatile("v_mfma_f32_16x16x32_bf16 %0, %1, %2, %0"                   \
                   : "+v"(acc[mf_][NF1]) : "v"(af[mf_]), "v"(BV1));            \
    }                                                                          \
    __builtin_amdgcn_s_setprio(0);                                             \
  } while (0)

#define PHASE_SYNC()                                                           \
  do {                                                                         \
    __builtin_amdgcn_s_barrier();                                              \
    asm volatile("s_waitcnt lgkmcnt(0)" ::: "memory");                         \
    __builtin_amdgcn_sched_barrier(0);                                         \
  } while (0)

  f32x4 acc[8][4];
#pragma unroll
  for (int i = 0; i < 8; ++i)
#pragma unroll
    for (int j = 0; j < 4; ++j) acc[i][j] = (f32x4)(0.0f);

  // prologue: A(0), B(0), A(1); land tiles' A(0)/B(0) (vmcnt(4) keeps A(1))
  STAGEH(0, 1, 0); STAGEH(0, 1, 1);
  STAGEH(0, 0, 0); STAGEH(0, 0, 1);
  STAGEH(1, 1, 0); STAGEH(1, 1, 1);
  asm volatile("s_waitcnt vmcnt(4)" ::: "memory");
  __builtin_amdgcn_s_barrier();

  for (int t = 0; t < T; ++t) {
    const int par = t & 1;
    const unsigned short* Ab_ = lds + (ahalf + par) * 8192 + alo;
    const unsigned short* Bb_ = lds + (4 + bhalf + par) * 8192 + bsub;
    short8 af[8], b0, b1;
    // ---- Ph1: stage B(t+1)h0; A-kk0 + B01-kk0; MFMA (kk0, nf0-1) ----
    STAGEH(t + 1, 0, 0);
#pragma unroll
    for (int mf = 0; mf < 8; ++mf)
      af[mf] = *reinterpret_cast<const short8*>(Ab_ + mf * 1024 + g0);
    b0 = *reinterpret_cast<const short8*>(Bb_ + 0 * 1024 + g0);
    b1 = *reinterpret_cast<const short8*>(Bb_ + 1 * 1024 + g0);
    PHASE_SYNC();
    MFMA16(b0, b1, 0, 1);
    __builtin_amdgcn_s_barrier();
    // ---- Ph2: stage B(t+1)h1; B23-kk0; MFMA (kk0, nf2-3) ----
    STAGEH(t + 1, 0, 1);
    b0 = *reinterpret_cast<const short8*>(Bb_ + 2 * 1024 + g0);
    b1 = *reinterpret_cast<const short8*>(Bb_ + 3 * 1024 + g0);
    PHASE_SYNC();
    MFMA16(b0, b1, 2, 3);
    __builtin_amdgcn_s_barrier();
    // ---- Ph3: A-kk1 + B23-kk1; MFMA (kk1, nf2-3) ----
#pragma unroll
    for (int mf = 0; mf < 8; ++mf)
      af[mf] = *reinterpret_cast<const short8*>(Ab_ + mf * 1024 + g1);
    b0 = *reinterpret_cast<const short8*>(Bb_ + 2 * 1024 + g1);
    b1 = *reinterpret_cast<const short8*>(Bb_ + 3 * 1024 + g1);
    PHASE_SYNC();
    MFMA16(b0, b1, 2, 3);
    __builtin_amdgcn_s_barrier();
    // ---- Ph4: stage A(t+2) h0+h1; B01-kk1; vmcnt(4); MFMA (kk1, nf0-1) ----
    STAGEH(t + 2, 1, 0); STAGEH(t + 2, 1, 1);
    b0 = *reinterpret_cast<const short8*>(Bb_ + 0 * 1024 + g1);
    b1 = *reinterpret_cast<const short8*>(Bb_ + 1 * 1024 + g1);
    asm volatile("s_waitcnt vmcnt(4)" ::: "memory");
    PHASE_SYNC();
    MFMA16(b0, b1, 0, 1);
    __builtin_amdgcn_s_barrier();
  }
#undef STAGEH
#undef MFMA16
#undef PHASE_SYNC

  // epilogue: C/D layout col=lane&15, row=(lane>>4)*4+reg  [R7-R9 validated]
#pragma unroll
  for (int mf = 0; mf < 8; ++mf) {
    const int rb = (bm << 8) + wm + mf * 16 + ((lane >> 4) << 2);
#pragma unroll
    for (int nf = 0; nf < 4; ++nf) {
      const int col = (bn << 8) + wn + nf * 16 + (lane & 15);
#pragma unroll
      for (int r = 0; r < 4; ++r)
        Cp[(size_t)(rb + r) * NB + col] = acc[mf][nf][r];
    }
  }
}

// ---- LDS-tiled conv (R9-validated): block = (uo, v-half, 32-n), all 16 co ----
__global__ __launch_bounds__(256) void conv_lds_kernel(
    const float* __restrict__ za, const float* __restrict__ zb,
    const float* __restrict__ zh, const float* __restrict__ w,
    const float* __restrict__ bias, unsigned short* __restrict__ tT) {
  __shared__ float zl[24 * 18 * 32];
  __shared__ float wl[1152];
  __shared__ float bl[16];
  const int b = blockIdx.x;
  const int nt = b & 31, vh = (b >> 5) & 1, uo = b >> 6;
  const int n0 = nt * 32;
  const int tid = threadIdx.x;
#pragma unroll
  for (int it = 0; it < 5; ++it) {
    const int idx = it * 256 + tid;
    if (idx < 1152) wl[idx] = w[idx];
  }
  if (tid < 16) bl[tid] = bias[tid];
  const int nl4 = (tid & 7) * 4;
#pragma unroll
  for (int it = 0; it < 13; ++it) {
    const int R = it * 32 + (tid >> 3);
    if (R < 408) {
      const int ci = R / 51;
      const int rem = R - ci * 51;
      const int kh = rem / 17;
      const int vi = rem - kh * 17;
      const int u = 2 * uo + kh;
      const int v = vh * 16 + vi;
      float4 val = make_float4(0.f, 0.f, 0.f, 0.f);
      if (u < 32 && v < 32) {
        const size_t g = ((size_t)(ci * 1024 + u * 32 + v)) * 1024 + n0 + nl4;
        const float4 a4 = *reinterpret_cast<const float4*>(za + g);
        const float4 b4 = *reinterpret_cast<const float4*>(zb + g);
        val = make_float4(a4.x + b4.x, a4.y + b4.y, a4.z + b4.z, a4.w + b4.w);
      }
      *reinterpret_cast<float4*>(zl + ((ci * 3 + kh) * 18 + vi) * 32 + nl4) = val;
    }
  }
  __syncthreads();
  const int nl = tid & 31;
  const int cop = tid >> 5;
  const float hom = zh[n0 + nl];
  float acc[2][8];
#pragma unroll
  for (int c = 0; c < 2; ++c) {
    const float bb = bl[cop + c * 8] * hom;
#pragma unroll
    for (int vo = 0; vo < 8; ++vo) acc[c][vo] = bb;
  }
  for (int ci = 0; ci < 8; ++ci) {
#pragma unroll
    for (int kh = 0; kh < 3; ++kh) {
      const float* zr = zl + (ci * 3 + kh) * (18 * 32) + nl;
      float zv[17];
#pragma unroll
      for (int vi = 0; vi < 17; ++vi) zv[vi] = zr[vi * 32];
#pragma unroll
      for (int c = 0; c < 2; ++c) {
        const int co = cop + c * 8;
        const float* wp = wl + ((co * 8 + ci) * 3 + kh) * 3;
#pragma unroll
        for (int kw = 0; kw < 3; ++kw) {
          const float wv = wp[kw];
#pragma unroll
          for (int vo = 0; vo < 8; ++vo) acc[c][vo] += wv * zv[2 * vo + kw];
        }
      }
    }
  }
#pragma unroll
  for (int c = 0; c < 2; ++c) {
    const int co = cop + c * 8;
    unsigned short o[8];
#pragma unroll
    for (int vo = 0; vo < 8; ++vo) o[vo] = f2bf(acc[c][vo]);
    uint4 pv;
    pv.x = (unsigned)o[0] | ((unsigned)o[1] << 16);
    pv.y = (unsigned)o[2] | ((unsigned)o[3] << 16);
    pv.z = (unsigned)o[4] | ((unsigned)o[5] << 16);
    pv.w = (unsigned)o[6] | ((unsigned)o[7] << 16);
    *reinterpret_cast<uint4*>(
        tT + (size_t)(n0 + nl) * KP2 + co * 256 + uo * 16 + vh * 8) = pv;
  }
}

// ---- tT rows 4096..4159: hom row + zero pad ----
__global__ __launch_bounds__(256) void homrow_kernel(
    const float* __restrict__ zh, unsigned short* __restrict__ tT) {
  const int n = blockIdx.x * 256 + threadIdx.x;
  unsigned short* p = tT + (size_t)n * KP2 + 4096;
  uint4 z4 = make_uint4(0u, 0u, 0u, 0u);
  uint4 h4 = z4;
  h4.x = (unsigned)f2bf(zh[n]);
  *reinterpret_cast<uint4*>(p) = h4;
#pragma unroll
  for (int i = 1; i < 8; ++i) *reinterpret_cast<uint4*>(p + i * 8) = z4;
}

// ---- final sum of 4 split-K partials -> d_out rows 0..4095 ----
__global__ __launch_bounds__(256) void sum4_kernel(
    const float* __restrict__ p, float* __restrict__ out, int n4) {
  const int i = blockIdx.x * 256 + threadIdx.x;
  if (i >= n4) return;
  const size_t stride4 = (size_t)M2 * NB / 4;
  const float4* p4 = (const float4*)p;
  float4 a = p4[i];
  float4 b = p4[i + stride4];
  float4 c = p4[i + 2 * stride4];
  float4 d = p4[i + 3 * stride4];
  float4 r;
  r.x = (a.x + b.x) + (c.x + d.x);
  r.y = (a.y + b.y) + (c.y + d.y);
  r.z = (a.z + b.z) + (c.z + d.z);
  r.w = (a.w + b.w) + (c.w + d.w);
  reinterpret_cast<float4*>(out)[i] = r;
}

// ---- out row 4096: wave-per-column dot over bf16 A2 row x tT ----
__global__ __launch_bounds__(256) void outrow_kernel(
    const unsigned short* __restrict__ A2row,
    const unsigned short* __restrict__ tT, float* __restrict__ out) {
  const int wid = threadIdx.x >> 6, lane = threadIdx.x & 63;
  const int n = blockIdx.x * 4 + wid;
  const unsigned short* trow = tT + (size_t)n * KP2;
  float acc = 0.f;
#pragma unroll
  for (int it = 0; it < 9; ++it) {
    const int i8 = it * 64 + lane;
    if (i8 < KP2 / 8) {
      short8 tv = *reinterpret_cast<const short8*>(trow + i8 * 8);
      short8 av = *reinterpret_cast<const short8*>(A2row + i8 * 8);
#pragma unroll
      for (int j = 0; j < 8; ++j)
        acc += bf2f((unsigned short)tv[j]) * bf2f((unsigned short)av[j]);
    }
  }
#pragma unroll
  for (int m = 1; m <= 32; m <<= 1) acc += __shfl_xor(acc, m);
  if (lane == 0) out[(size_t)4096 * NB + n] = acc;
}

extern "C" void kernel_launch(void* const* d_in, const int* in_sizes, int n_in,
                              void* d_out, int out_size, void* d_ws, size_t ws_size,
                              hipStream_t stream) {
  const float* w    = (const float*)d_in[0];  // (16,8,3,3)
  const float* bias = (const float*)d_in[1];  // (16,)
  const float* A    = (const float*)d_in[2];  // (4097,4097)
  const float* Ainv = (const float*)d_in[3];  // (8193,8193)
  const float* x    = (const float*)d_in[4];  // (8193,1024)
  float* out = (float*)d_out;                 // (4097,1024)

  // Workspace (227.8 MB <= proven 231.5): R9 plan
  char* ws = (char*)d_ws;
  const size_t o_xT = (size_t)M1 * KP1 * 2;
  const size_t o_z2 = o_xT + (size_t)NB * KP1 * 2;
  const size_t o_tT = o_z2 + (size_t)2 * M1 * NB * 4;
  const size_t o_zh = o_tT + (size_t)NB * KP2 * 2;
  unsigned short* Ainv_b = (unsigned short*)ws;
  unsigned short* xT_b   = (unsigned short*)(ws + o_xT);
  float*          z2     = (float*)(ws + o_z2);
  unsigned short* tT_b   = (unsigned short*)(ws + o_tT);
  float*          zh     = (float*)(ws + o_zh);
  unsigned short* A2_b   = (unsigned short*)ws;
  float*          outp   = (float*)(ws + (size_t)OUT_DIM * KP2 * 2);
  (void)ws_size; (void)in_sizes; (void)n_in; (void)out_size;

  hipFuncSetAttribute((const void*)gemm_dp<129, 2, 2, M1>,
                      hipFuncAttributeMaxDynamicSharedMemorySize, 131072);
  hipFuncSetAttribute((const void*)gemm_dp<65, 4, 1, M2>,
                      hipFuncAttributeMaxDynamicSharedMemorySize, 131072);

  // 1) zero zh (hom accumulator)
  zero_kernel<<<1, 256, 0, stream>>>((float4*)zh, 256);
  // 2) Ainv rows 0..8191 -> padded bf16
  cvt_pad_kernel<<<(M1 * KP1 / 4) / 256, 256, 0, stream>>>(
      Ainv, Ainv_b, IN_DIM, IN_DIM, M1, KP1);
  // 3) x -> x^T bf16 + fused zh = Ainv[8192,:] @ x
  transpose_cvt_zh_kernel<<<(KP1 / 32) * (NB / 32), 256, 0, stream>>>(
      x, xT_b, Ainv + (size_t)8192 * IN_DIM, zh, IN_DIM, NB, KP1);
  // 4) z{a,b} = Ainv @ x  (8-barrier 4-phase GEMM, exactly 256 blocks)
  gemm_dp<129, 2, 2, M1><<<256, 512, 131072, stream>>>(
      Ainv_b, xT_b, z2, KP1);
  // 5) t^T rows 0..4095 = conv(za+zb, hom=zh)  (LDS-tiled, 1024 blocks)
  conv_lds_kernel<<<1024, 256, 0, stream>>>(
      z2, z2 + (size_t)M1 * NB, zh, w, bias, tT_b);
  // 5b) t^T rows 4096..4159 = hom + zero pad
  homrow_kernel<<<4, 256, 0, stream>>>(zh, tT_b);
  // 6) A rows 0..4096 -> padded bf16 (aliases dead Ainv_b)
  cvt_pad_kernel<<<(OUT_DIM * KP2 / 4 + 255) / 256, 256, 0, stream>>>(
      A, A2_b, OUT_DIM, OUT_DIM, OUT_DIM, KP2);
  // 7) outp[0..3] = A @ t  (8-barrier 4-phase GEMM, exactly 256 blocks)
  gemm_dp<65, 4, 1, M2><<<256, 512, 131072, stream>>>(
      A2_b, tT_b, outp, KP2);
  // 8) out rows 0..4095 = sum of partials
  sum4_kernel<<<(M2 * NB / 4) / 256, 256, 0, stream>>>(
      outp, out, M2 * NB / 4);
  // 9) out row 4096 = A2[4096,:] @ t
  outrow_kernel<<<NB / 4, 256, 0, stream>>>(
      A2_b + (size_t)4096 * KP2, tT_b, out);
}